// Round 3
// baseline (3293.726 us; speedup 1.0000x reference)
//
#include <hip/hip_runtime.h>
#include <hip/hip_bf16.h>
#include <math.h>

#define NN 20000
#define NE 640000
#define C 128
#define DE 64
#define ZD 320
#define HD 512
#define G 32
#define LL 3
#define EPSV 1e-5f

typedef __attribute__((ext_vector_type(8))) short bf16x8;
typedef __attribute__((ext_vector_type(4))) float f32x4;

__device__ __forceinline__ ushort f2bf(float f) {
    __hip_bfloat16 h = __float2bfloat16(f);
    return *reinterpret_cast<ushort*>(&h);
}
__device__ __forceinline__ float bf2f(ushort u) {
    return __uint_as_float(((unsigned)u) << 16);
}

// ---------------- graph counting ----------------
__global__ __launch_bounds__(256) void k_gcount(const int* __restrict__ nb, int* __restrict__ gcount) {
    int i = blockIdx.x * 256 + threadIdx.x;
    if (i < NN) atomicAdd(&gcount[nb[i]], 1);
}

// ---------------- edge sort by dst (counting sort) ----------------
__global__ __launch_bounds__(256) void k_hist(const int* __restrict__ ei, int* __restrict__ deg) {
    int e = blockIdx.x * 256 + threadIdx.x;
    atomicAdd(&deg[ei[NE + e]], 1);
}
__global__ __launch_bounds__(256) void k_scan1(const int* __restrict__ deg, int* __restrict__ cursor,
                                               int* __restrict__ bsum) {
    __shared__ int sh[256];
    int t = threadIdx.x, b = blockIdx.x, i = b * 256 + t;
    int v = (i < NN) ? deg[i] : 0;
    sh[t] = v; __syncthreads();
    for (int off = 1; off < 256; off <<= 1) {
        int u = (t >= off) ? sh[t - off] : 0;
        __syncthreads();
        sh[t] += u;
        __syncthreads();
    }
    if (i < NN) cursor[i] = sh[t] - v;          // exclusive within block
    if (t == 255) bsum[b] = sh[255];
}
__global__ void k_scan2(const int* __restrict__ bsum, int* __restrict__ boff, int nb) {
    int r = 0;
    for (int b = 0; b < nb; ++b) { boff[b] = r; r += bsum[b]; }
}
__global__ __launch_bounds__(256) void k_scan3(int* __restrict__ cursor, const int* __restrict__ boff) {
    int i = blockIdx.x * 256 + threadIdx.x;
    if (i < NN) cursor[i] += boff[blockIdx.x];
}
__global__ __launch_bounds__(256) void k_scatter(const int* __restrict__ ei, int* __restrict__ cursor,
                                                 int* __restrict__ perm) {
    int e = blockIdx.x * 256 + threadIdx.x;
    int d = ei[NE + e];
    int pos = atomicAdd(&cursor[d], 1);
    perm[pos] = e;
}

// ---------------- casts ----------------
__global__ __launch_bounds__(256) void k_cast_x(const float* __restrict__ in, ushort* __restrict__ out) {
    int idx = blockIdx.x * 256 + threadIdx.x;    // n/4 threads
    float4 v = ((const float4*)in)[idx];
    ushort4 o;
    o.x = f2bf(v.x); o.y = f2bf(v.y); o.z = f2bf(v.z); o.w = f2bf(v.w);
    ((ushort4*)out)[idx] = o;
}

// ---------------- build combined edge weights (bf16) ----------------
__global__ __launch_bounds__(256) void k_prepw(
    const float* __restrict__ Wf, const float* __restrict__ bfv,
    const float* __restrict__ Ws, const float* __restrict__ bsv,
    ushort* __restrict__ Wc, float* __restrict__ bc)
{
    int idx = blockIdx.x * 256 + threadIdx.x;    // 256*320 = 81920
    int r = idx / 320, k = idx - r * 320;
    int w = r >> 6, j = (r >> 4) & 3, off = r & 15;
    int ch = w * 32 + (j & 1) * 16 + off;
    const float* W = (j < 2) ? Wf : Ws;
    Wc[idx] = f2bf(W[(size_t)ch * ZD + k]);
    if (k == 0) bc[r] = ((j < 2) ? bfv : bsv)[ch];
}

// ---------------- CGConv edge kernel (MFMA, dst-sorted, LDS-reduced) ----------------
__global__ __launch_bounds__(256) void k_edge_mfma(
    const ushort* __restrict__ x16, const int* __restrict__ ei,
    const int* __restrict__ perm, const float* __restrict__ ea,
    const ushort* __restrict__ Wc, const float* __restrict__ bc,
    float* __restrict__ xnew)
{
    __shared__ ushort zt[64][328];
    __shared__ int s_src[64], s_dst[64], s_perm[64], s_seg[64], s_segnode[64];
    __shared__ int s_nseg;
    const int tid = threadIdx.x;
    const int e0 = blockIdx.x * 64;
    if (tid < 64) {
        int p = perm[e0 + tid];
        s_perm[tid] = p;
        s_src[tid] = ei[p];
        s_dst[tid] = ei[NE + p];
    }
    __syncthreads();
    if (tid == 0) {
        int sgn = 0;
        s_seg[0] = 0; s_segnode[0] = s_dst[0];
        for (int i = 1; i < 64; ++i) {
            if (s_dst[i] != s_dst[i - 1]) { ++sgn; s_segnode[sgn] = s_dst[i]; }
            s_seg[i] = sgn;
        }
        s_nseg = sgn + 1;
    }

    // gather: 64 edges x 40 chunks (8 bf16 each), 10 per thread
    for (int it = 0; it < 10; ++it) {
        int idx = tid + it * 256;
        int e = idx / 40;
        int r = idx - e * 40;
        if (r < 32) {
            const ushort* s = (r < 16)
                ? x16 + (size_t)s_dst[e] * C + r * 8
                : x16 + (size_t)s_src[e] * C + (r - 16) * 8;
            *(uint4*)(&zt[e][r * 8]) = *(const uint4*)s;
        } else {
            const float* s = ea + (size_t)s_perm[e] * DE + (r - 32) * 8;
            float4 u = *(const float4*)s;
            float4 v = *(const float4*)(s + 4);
            ushort4 o0, o1;
            o0.x = f2bf(u.x); o0.y = f2bf(u.y); o0.z = f2bf(u.z); o0.w = f2bf(u.w);
            o1.x = f2bf(v.x); o1.y = f2bf(v.y); o1.z = f2bf(v.z); o1.w = f2bf(v.w);
            *(ushort4*)(&zt[e][r * 8]) = o0;
            *(ushort4*)(&zt[e][r * 8 + 4]) = o1;
        }
    }
    __syncthreads();

    const int w = tid >> 6, l = tid & 63;
    const int lr = l & 15;
    const int kp = (l >> 4) * 8;
    f32x4 acc[4][4];
#pragma unroll
    for (int rt = 0; rt < 4; ++rt)
#pragma unroll
        for (int j = 0; j < 4; ++j) acc[rt][j] = (f32x4){0.f, 0.f, 0.f, 0.f};

    for (int kk = 0; kk < 10; ++kk) {
        const int k0 = kk * 32 + kp;
        bf16x8 a[4], b[4];
#pragma unroll
        for (int rt = 0; rt < 4; ++rt)
            a[rt] = *(const bf16x8*)(&zt[rt * 16 + lr][k0]);
#pragma unroll
        for (int j = 0; j < 4; ++j) {
            int row = (w * 4 + j) * 16 + lr;
            b[j] = *(const bf16x8*)(Wc + (size_t)row * ZD + k0);
        }
#pragma unroll
        for (int rt = 0; rt < 4; ++rt)
#pragma unroll
            for (int j = 0; j < 4; ++j)
                acc[rt][j] = __builtin_amdgcn_mfma_f32_16x16x32_bf16(a[rt], b[j], acc[rt][j], 0, 0, 0);
    }
    __syncthreads();                 // all zt reads done -> reuse as accumulator

    float* accL = (float*)zt;        // [64 segs][128 ch] = 32 KB (< zt size)
    for (int i = tid; i < 8192; i += 256) accL[i] = 0.f;
    __syncthreads();

    const int ro = (l >> 4) * 4;
    const float bg0 = bc[w * 64 + lr];
    const float bg1 = bc[w * 64 + 16 + lr];
    const float bs0 = bc[w * 64 + 32 + lr];
    const float bs1 = bc[w * 64 + 48 + lr];
#pragma unroll
    for (int rt = 0; rt < 4; ++rt) {
#pragma unroll
        for (int j2 = 0; j2 < 2; ++j2) {
            const float bg = j2 ? bg1 : bg0;
            const float bs = j2 ? bs1 : bs0;
            const int chl = w * 32 + j2 * 16 + lr;
#pragma unroll
            for (int q = 0; q < 4; ++q) {
                int e = rt * 16 + ro + q;
                float g = acc[rt][j2][q] + bg;
                float s = acc[rt][j2 + 2][q] + bs;
                float gate = 1.0f / (1.0f + __expf(-g));
                float sp = fmaxf(s, 0.0f) + __logf(1.0f + __expf(-fabsf(s)));
                atomicAdd(&accL[s_seg[e] * 128 + chl], gate * sp);
            }
        }
    }
    __syncthreads();

    const int tot = s_nseg * 128;
    for (int i = tid; i < tot; i += 256)
        unsafeAtomicAdd(xnew + (size_t)s_segnode[i >> 7] * C + (i & 127), accL[i]);
}

// ---------------- MLP GEMM1 (MFMA): h16 = bf16(x @ W1^T + b1), col stats ----------------
__global__ __launch_bounds__(256) void k_mlp1_mfma(
    const ushort* __restrict__ xb16, const ushort* __restrict__ W116,
    const float* __restrict__ b1, ushort* __restrict__ h16,
    float* __restrict__ colsum, float* __restrict__ colsq)
{
    __shared__ ushort xs[64][136];
    const int tid = threadIdx.x;
    const int n0 = blockIdx.x * 64;
    const int ch0 = blockIdx.y * 128;
#pragma unroll
    for (int it = 0; it < 4; ++it) {
        int idx = tid + it * 256;       // 1024 chunks
        int e = idx >> 4, c = (idx & 15) * 8;
        int rr = n0 + e; if (rr >= NN) rr = NN - 1;
        *(uint4*)(&xs[e][c]) = *(const uint4*)(xb16 + (size_t)rr * C + c);
    }
    __syncthreads();
    const int w = tid >> 6, l = tid & 63, lr = l & 15, kp = (l >> 4) * 8;
    const int cb = ch0 + w * 32;
    f32x4 acc[4][2];
#pragma unroll
    for (int rt = 0; rt < 4; ++rt) { acc[rt][0] = (f32x4){0,0,0,0}; acc[rt][1] = (f32x4){0,0,0,0}; }
    for (int kk = 0; kk < 4; ++kk) {
        int k0 = kk * 32 + kp;
        bf16x8 a[4], b[2];
#pragma unroll
        for (int rt = 0; rt < 4; ++rt) a[rt] = *(const bf16x8*)(&xs[rt * 16 + lr][k0]);
#pragma unroll
        for (int j = 0; j < 2; ++j) b[j] = *(const bf16x8*)(W116 + (size_t)(cb + j * 16 + lr) * C + k0);
#pragma unroll
        for (int rt = 0; rt < 4; ++rt)
#pragma unroll
            for (int j = 0; j < 2; ++j)
                acc[rt][j] = __builtin_amdgcn_mfma_f32_16x16x32_bf16(a[rt], b[j], acc[rt][j], 0, 0, 0);
    }
    const int ro = (l >> 4) * 4;
    float ps[2] = {0.f, 0.f}, pq[2] = {0.f, 0.f};
#pragma unroll
    for (int j = 0; j < 2; ++j) {
        const int ch = cb + j * 16 + lr;
        const float bv = b1[ch];
#pragma unroll
        for (int rt = 0; rt < 4; ++rt) {
#pragma unroll
            for (int q = 0; q < 4; ++q) {
                int row = n0 + rt * 16 + ro + q;
                float hv = acc[rt][j][q] + bv;
                if (row < NN) {
                    h16[(size_t)row * HD + ch] = f2bf(hv);
                    ps[j] += hv; pq[j] += hv * hv;
                }
            }
        }
    }
#pragma unroll
    for (int j = 0; j < 2; ++j) {
        ps[j] += __shfl_xor(ps[j], 16); ps[j] += __shfl_xor(ps[j], 32);
        pq[j] += __shfl_xor(pq[j], 16); pq[j] += __shfl_xor(pq[j], 32);
    }
    if (l < 16) {
#pragma unroll
        for (int j = 0; j < 2; ++j) {
            unsafeAtomicAdd(colsum + cb + j * 16 + lr, ps[j]);
            unsafeAtomicAdd(colsq + cb + j * 16 + lr, pq[j]);
        }
    }
}

__global__ void k_bnstats(const float* __restrict__ colsum, const float* __restrict__ colsq,
                          const float* __restrict__ g1, const float* __restrict__ be1,
                          float* __restrict__ bn_a, float* __restrict__ bn_b) {
    int c = threadIdx.x;   // 512
    float m = colsum[c] * (1.0f / NN);
    float v = colsq[c] * (1.0f / NN) - m * m;
    float istd = rsqrtf(fmaxf(v, 0.f) + EPSV);
    float a = g1[c] * istd;
    bn_a[c] = a;
    bn_b[c] = fmaf(-m, a, be1[c]);
}

// ---------------- MLP GEMM2 (MFMA): x = xres + relu(a*h+b) @ W2^T + b2 ----------------
__global__ __launch_bounds__(256) void k_mlp2_mfma(
    const ushort* __restrict__ h16, const float* __restrict__ bn_a, const float* __restrict__ bn_b,
    const ushort* __restrict__ W216, const float* __restrict__ b2,
    const float* __restrict__ xres, float* __restrict__ xout)
{
    __shared__ ushort hs[64][136];
    const int tid = threadIdx.x;
    const int n0 = blockIdx.x * 64;
    const int w = tid >> 6, l = tid & 63, lr = l & 15, kp = (l >> 4) * 8;
    f32x4 acc[4][2];
#pragma unroll
    for (int rt = 0; rt < 4; ++rt) { acc[rt][0] = (f32x4){0,0,0,0}; acc[rt][1] = (f32x4){0,0,0,0}; }

    for (int kc = 0; kc < 4; ++kc) {
#pragma unroll
        for (int it = 0; it < 4; ++it) {
            int idx = tid + it * 256;
            int e = idx >> 4, c = (idx & 15) * 8;
            int rr = n0 + e; if (rr >= NN) rr = NN - 1;
            int k = kc * 128 + c;
            bf16x8 hv = *(const bf16x8*)(h16 + (size_t)rr * HD + k);
            ushort o[8];
#pragma unroll
            for (int m = 0; m < 8; ++m) {
                float f = bf2f((ushort)hv[m]);
                f = fmaf(bn_a[k + m], f, bn_b[k + m]);
                o[m] = f2bf(fmaxf(f, 0.f));
            }
            *(uint4*)(&hs[e][c]) = *(uint4*)o;
        }
        __syncthreads();
        for (int kk = 0; kk < 4; ++kk) {
            int k0 = kk * 32 + kp;
            bf16x8 a[4], b[2];
#pragma unroll
            for (int rt = 0; rt < 4; ++rt) a[rt] = *(const bf16x8*)(&hs[rt * 16 + lr][k0]);
#pragma unroll
            for (int j = 0; j < 2; ++j)
                b[j] = *(const bf16x8*)(W216 + (size_t)(w * 32 + j * 16 + lr) * HD + kc * 128 + k0);
#pragma unroll
            for (int rt = 0; rt < 4; ++rt)
#pragma unroll
                for (int j = 0; j < 2; ++j)
                    acc[rt][j] = __builtin_amdgcn_mfma_f32_16x16x32_bf16(a[rt], b[j], acc[rt][j], 0, 0, 0);
        }
        __syncthreads();
    }
    const int ro = (l >> 4) * 4;
#pragma unroll
    for (int j = 0; j < 2; ++j) {
        const int ch = w * 32 + j * 16 + lr;
        const float bv = b2[ch];
#pragma unroll
        for (int rt = 0; rt < 4; ++rt) {
#pragma unroll
            for (int q = 0; q < 4; ++q) {
                int row = n0 + rt * 16 + ro + q;
                if (row < NN)
                    xout[(size_t)row * C + ch] = xres[(size_t)row * C + ch] + acc[rt][j][q] + bv;
            }
        }
    }
}

// ---------------- graph LayerNorm ----------------
__global__ __launch_bounds__(256) void k_lnstats(
    const float* __restrict__ x2, const int* __restrict__ nb_arr,
    float* __restrict__ gsum, float* __restrict__ gsq)
{
    const int tid = threadIdx.x;
    const int node = blockIdx.x * 64 + (tid >> 2);
    const int sub = tid & 3;
    if (node >= NN) return;
    const float4* row = (const float4*)(x2 + (size_t)node * C);
    float s = 0.f, q = 0.f;
#pragma unroll
    for (int t = 0; t < 8; ++t) {
        float4 v = row[sub + 4 * t];
        s += v.x + v.y + v.z + v.w;
        q += v.x * v.x + v.y * v.y + v.z * v.z + v.w * v.w;
    }
    s += __shfl_xor(s, 1); q += __shfl_xor(q, 1);
    s += __shfl_xor(s, 2); q += __shfl_xor(q, 2);
    if (sub == 0) {
        int g = nb_arr[node];
        unsafeAtomicAdd(&gsum[g], s);
        unsafeAtomicAdd(&gsq[g], q);
    }
}

__global__ void k_lnfin(const float* __restrict__ gsum, const float* __restrict__ gsq,
                        const int* __restrict__ gcount,
                        float* __restrict__ gmean, float* __restrict__ gistd) {
    int g = threadIdx.x;
    float cnt = fmaxf((float)gcount[g], 1.0f) * (float)C;
    float m = gsum[g] / cnt;
    float v = gsq[g] / cnt - m * m;
    gmean[g] = m;
    gistd[g] = rsqrtf(fmaxf(v, 0.f) + EPSV);
}

__global__ __launch_bounds__(256) void k_lnapply(
    const float* __restrict__ x2, const int* __restrict__ nb_arr,
    const float* __restrict__ gmean, const float* __restrict__ gistd,
    const float* __restrict__ lnw, const float* __restrict__ lnb, float* __restrict__ out)
{
    int idx = blockIdx.x * 256 + threadIdx.x;
    int n = idx >> 7, c = idx & 127;
    int g = nb_arr[n];
    out[idx] = (x2[idx] - gmean[g]) * gistd[g] * lnw[c] + lnb[c];
}

// ---------------- launcher ----------------
extern "C" void kernel_launch(void* const* d_in, const int* in_sizes, int n_in,
                              void* d_out, int out_size, void* d_ws, size_t ws_size,
                              hipStream_t stream) {
    const float* x_in = (const float*)d_in[0];
    const int* node_batch = (const int*)d_in[1];
    const int* ei = (const int*)d_in[2];
    const float* ea = (const float*)d_in[3];
    const float* Wf = (const float*)d_in[4];
    const float* bfv = (const float*)d_in[5];
    const float* Ws = (const float*)d_in[6];
    const float* bsv = (const float*)d_in[7];
    const float* W1 = (const float*)d_in[8];
    const float* b1 = (const float*)d_in[9];
    const float* g1 = (const float*)d_in[10];
    const float* be1 = (const float*)d_in[11];
    const float* W2 = (const float*)d_in[12];
    const float* b2 = (const float*)d_in[13];
    const float* lnw = (const float*)d_in[14];
    const float* lnb = (const float*)d_in[15];
    float* out = (float*)d_out;

    const size_t NC = (size_t)NN * C;       // 2,560,000
    const size_t NH = (size_t)NN * HD;      // 10,240,000
    float* p = (float*)d_ws;
    float* xa = p; p += NC;
    float* xb = p; p += NC;
    ushort* h16 = (ushort*)p; p += NH / 2;
    ushort* bfx = (ushort*)p; p += NC / 2;
    ushort* Wce = (ushort*)p; p += 40960;          // 81920 ushorts
    ushort* W116 = (ushort*)p; p += 98304;         // 3*512*128 ushorts
    ushort* W216 = (ushort*)p; p += 98304;
    float* bc = p; p += 256;
    float* bn_a = p; p += 512;
    float* bn_b = p; p += 512;
    float* colsum = p; p += 512;
    float* colsq = p; p += 512;                    // contiguous with colsum
    float* gsum = p; p += 32;
    float* gsq = p; p += 32;                       // contiguous with gsum
    float* gmean = p; p += 32;
    float* gistd = p; p += 32;
    int* gcount = (int*)p; p += 32;
    int* deg = (int*)p; p += NN;
    int* cursor = (int*)p; p += NN;
    int* bsum = (int*)p; p += 128;
    int* boff = (int*)p; p += 128;
    int* perm = (int*)p; p += NE;

    const int NB_SCAN = (NN + 255) / 256;          // 79

    // ---- one-time per call: sort edges by dst, graph counts, weight casts ----
    hipMemsetAsync(deg, 0, NN * 4, stream);
    k_hist<<<NE / 256, 256, 0, stream>>>(ei, deg);
    k_scan1<<<NB_SCAN, 256, 0, stream>>>(deg, cursor, bsum);
    k_scan2<<<1, 1, 0, stream>>>(bsum, boff, NB_SCAN);
    k_scan3<<<NB_SCAN, 256, 0, stream>>>(cursor, boff);
    k_scatter<<<NE / 256, 256, 0, stream>>>(ei, cursor, perm);

    hipMemsetAsync(gcount, 0, G * 4, stream);
    k_gcount<<<(NN + 255) / 256, 256, 0, stream>>>(node_batch, gcount);

    k_cast_x<<<(3 * HD * C) / 1024, 256, 0, stream>>>(W1, W116);
    k_cast_x<<<(3 * HD * C) / 1024, 256, 0, stream>>>(W2, W216);

    hipMemcpyAsync(xa, x_in, NC * 4, hipMemcpyDeviceToDevice, stream);

    for (int l = 0; l < LL; ++l) {
        k_cast_x<<<NC / 1024, 256, 0, stream>>>(xa, bfx);
        k_prepw<<<320, 256, 0, stream>>>(
            Wf + (size_t)l * C * ZD, bfv + (size_t)l * C,
            Ws + (size_t)l * C * ZD, bsv + (size_t)l * C, Wce, bc);
        hipMemcpyAsync(xb, xa, NC * 4, hipMemcpyDeviceToDevice, stream);
        k_edge_mfma<<<NE / 64, 256, 0, stream>>>(bfx, ei, perm, ea, Wce, bc, xb);

        k_cast_x<<<NC / 1024, 256, 0, stream>>>(xb, bfx);
        hipMemsetAsync(colsum, 0, 1024 * 4, stream);
        k_mlp1_mfma<<<dim3(313, 4), 256, 0, stream>>>(bfx,
            W116 + (size_t)l * HD * C, b1 + (size_t)l * HD, h16, colsum, colsq);
        k_bnstats<<<1, HD, 0, stream>>>(colsum, colsq,
            g1 + (size_t)l * HD, be1 + (size_t)l * HD, bn_a, bn_b);

        hipMemsetAsync(gsum, 0, 64 * 4, stream);
        k_mlp2_mfma<<<313, 256, 0, stream>>>(h16, bn_a, bn_b,
            W216 + (size_t)l * C * HD, b2 + (size_t)l * C, xb, xa);

        k_lnstats<<<(NN + 63) / 64, 256, 0, stream>>>(xa, node_batch, gsum, gsq);
        k_lnfin<<<1, G, 0, stream>>>(gsum, gsq, gcount, gmean, gistd);
        float* dstp = (l == LL - 1) ? out : xa;
        k_lnapply<<<(NN * C) / 256, 256, 0, stream>>>(xa, node_batch, gmean, gistd,
            lnw + (size_t)l * C, lnb + (size_t)l * C, dstp);
    }
}